// Round 6
// baseline (170.139 us; speedup 1.0000x reference)
//
#include <hip/hip_runtime.h>
#include <cmath>

// Shapes:
//  fused  [16,64,128,128] f32
//  hf1    [16, 9,256,256] f32
//  hf2    [16, 9,128,128] f32
//  conv_w [3,64,3,3] f32, conv_b [3] f32
//  out    [16,3,512,512] f32
//
// Pipeline:
//  K1 conv4<ICP>: ic-split partial conv, 4 rows x 2 cols per thread ->
//     part [64/ICP][16][3][128][128]
//  K2 reduce_tanh<NCH>: ll = tanh(sum part + bias)
//  K3 iwt_row2: 2 output rows per thread, fused double inverse-Haar.
//
// R5 post-mortem: all kernels < 40 us (harness 256MB ws-poison fills dominate the
// profile at ~40 us and are inside the timed window; ~75 us fixed overhead).
// Conv still latency-bound -> more ILP per thread via row reuse (1:36 load:FMA).

#define H1 128
#define W1 128
#define H2 256
#define W2 256
#define H3 512
#define W3 512
#define IN_CH 64
#define NB 16
#define PLANE (H1 * W1)            // 16384
#define LLSZ (NB * 3 * PLANE)      // 786432 floats per chunk

template <int ICP>
__global__ __launch_bounds__(256) void conv4_kernel(
    const float* __restrict__ fused,
    const float* __restrict__ cw,
    float* __restrict__ part)
{
    // block (64,4); grid (64/ICP, 8, 16). Thread: 4 output rows x 2 cols.
    const int tx    = threadIdx.x;                 // lane = w-pair
    const int ty    = threadIdx.y;
    const int chunk = blockIdx.x;
    const int g     = blockIdx.y * 4 + ty;         // row-group 0..31
    const int b     = blockIdx.z;
    const int hbase = g * 4;
    const int w0    = tx * 2;

    float acc[3][4][2];
    #pragma unroll
    for (int oc = 0; oc < 3; ++oc)
        #pragma unroll
        for (int j = 0; j < 4; ++j) { acc[oc][j][0] = 0.f; acc[oc][j][1] = 0.f; }

    const float* fc = fused + ((size_t)b * IN_CH + chunk * ICP) * PLANE;

    auto ld = [&](float2 R[6], int ic) {
        const float* fp = fc + (size_t)ic * PLANE;
        #pragma unroll
        for (int r = 0; r < 6; ++r) {
            const int hh = hbase + r - 1;
            if (((unsigned)hh) < (unsigned)H1) {
                R[r] = *(const float2*)(fp + hh * W1 + w0);
            } else { R[r].x = 0.f; R[r].y = 0.f; }
        }
    };

    auto comp = [&](const float2 R[6], int ic) {
        float v[6][4];
        #pragma unroll
        for (int r = 0; r < 6; ++r) {
            float left  = __shfl_up(R[r].y, 1, 64);
            float right = __shfl_down(R[r].x, 1, 64);
            if (tx == 0)  left = 0.f;    // w = -1
            if (tx == 63) right = 0.f;   // w = 128
            v[r][0] = left; v[r][1] = R[r].x; v[r][2] = R[r].y; v[r][3] = right;
        }
        #pragma unroll
        for (int oc = 0; oc < 3; ++oc) {
            const float* wp = cw + (oc * IN_CH + chunk * ICP + ic) * 9;  // uniform -> s_load
            #pragma unroll
            for (int kh = 0; kh < 3; ++kh) {
                #pragma unroll
                for (int kw = 0; kw < 3; ++kw) {
                    const float wv = wp[kh * 3 + kw];
                    #pragma unroll
                    for (int j = 0; j < 4; ++j) {
                        acc[oc][j][0] = fmaf(v[j + kh][kw],     wv, acc[oc][j][0]);
                        acc[oc][j][1] = fmaf(v[j + kh][kw + 1], wv, acc[oc][j][1]);
                    }
                }
            }
        }
    };

    // 2-deep software pipeline; no launch_bounds min-waves cap (R3 spill lesson).
    float2 A[6], B[6];
    ld(A, 0);
    for (int ic = 0; ic < ICP; ic += 2) {
        ld(B, ic + 1);
        comp(A, ic);
        if (ic + 2 < ICP) ld(A, ic + 2);
        comp(B, ic + 1);
    }

    const size_t cb0 = (size_t)chunk * LLSZ + (((size_t)b * 3) * H1) * W1;
    #pragma unroll
    for (int oc = 0; oc < 3; ++oc) {
        #pragma unroll
        for (int j = 0; j < 4; ++j) {
            float2 o; o.x = acc[oc][j][0]; o.y = acc[oc][j][1];
            *(float2*)(part + cb0 + ((size_t)oc * H1 + hbase + j) * W1 + w0) = o;
        }
    }
}

// part[NCH] -> ll = tanh(sum + bias). 1 thread = 4 px.
template <int NCH>
__global__ __launch_bounds__(256) void reduce_tanh_kernel(
    const float* __restrict__ part,
    const float* __restrict__ cb,
    float* __restrict__ ll)
{
    const int j = blockIdx.x * 256 + threadIdx.x;        // 196608
    const int c = (j >> 12) % 3;
    float4 s = *(const float4*)(part + 4 * (size_t)j);
    #pragma unroll
    for (int k = 1; k < NCH; ++k) {
        float4 p = *(const float4*)(part + (size_t)k * LLSZ + 4 * (size_t)j);
        s.x += p.x; s.y += p.y; s.z += p.z; s.w += p.w;
    }
    const float bias = cb[c];
    float4 o;
    o.x = tanhf(s.x + bias); o.y = tanhf(s.y + bias);
    o.z = tanhf(s.z + bias); o.w = tanhf(s.w + bias);
    *(float4*)(ll + 4 * (size_t)j) = o;
}

// One thread per hf1-row position: produces 2 output rows (8 px). 1.57M threads.
__global__ __launch_bounds__(256) void iwt_row2_kernel(
    const float* __restrict__ ll,    // [16,3,128,128] (tanh'd)
    const float* __restrict__ hf2,   // [16,9,128,128]
    const float* __restrict__ hf1,   // [16,9,256,256]
    float* __restrict__ out)         // [16,3,512,512]
{
    const int idx = blockIdx.x * 256 + threadIdx.x;   // 1572864
    const int k    = idx & 127;          // coarse col
    const int Hr   = (idx >> 7) & 255;   // level-1 row
    const int rest = idx >> 15;          // 0..47
    const int c = rest % 3;
    const int b = rest / 3;
    const int h = Hr >> 1;               // coarse row
    const int p = Hr & 1;                // level-1 sub-row

    const float llv = ll[(((size_t)(b * 3 + c)) * H1 + h) * W1 + k];

    const float* h2p = hf2 + (((size_t)(b * 9 + 3 * c)) * H1 + h) * W1 + k;
    const float a2 = h2p[0]         * 2.f - 1.f;   // LH
    const float b2 = h2p[PLANE]     * 2.f - 1.f;   // HL
    const float c2 = h2p[2 * PLANE] * 2.f - 1.f;   // HH
    const float sp = p ? 1.f : -1.f;
    const float m0 = 0.5f * (llv + sp * a2 - b2 - sp * c2);   // level-1 col 2k
    const float m1 = 0.5f * (llv + sp * a2 + b2 + sp * c2);   // level-1 col 2k+1

    const float* h1p = hf1 + ((size_t)(b * 9 + 3 * c)) * (H2 * W2) + (size_t)Hr * W2 + 2 * k;
    const float2 A  = *(const float2*)(h1p);
    const float2 Bv = *(const float2*)(h1p + H2 * W2);
    const float2 Cv = *(const float2*)(h1p + 2 * H2 * W2);
    const float a0 = A.x  * 2.f - 1.f, a1 = A.y  * 2.f - 1.f;
    const float b0 = Bv.x * 2.f - 1.f, b1 = Bv.y * 2.f - 1.f;
    const float c0 = Cv.x * 2.f - 1.f, c1 = Cv.y * 2.f - 1.f;

    float* ob = out + (((size_t)(b * 3 + c)) * H3 + 2 * (size_t)Hr) * W3 + 4 * k;
    float4 o;
    // r = 0 (sr = -1)
    o.x = 0.5f * (m0 - a0 - b0 + c0);
    o.y = 0.5f * (m0 - a0 + b0 - c0);
    o.z = 0.5f * (m1 - a1 - b1 + c1);
    o.w = 0.5f * (m1 - a1 + b1 - c1);
    *(float4*)(ob) = o;
    // r = 1 (sr = +1)
    o.x = 0.5f * (m0 + a0 - b0 - c0);
    o.y = 0.5f * (m0 + a0 + b0 + c0);
    o.z = 0.5f * (m1 + a1 - b1 - c1);
    o.w = 0.5f * (m1 + a1 + b1 + c1);
    *(float4*)(ob + W3) = o;
}

extern "C" void kernel_launch(void* const* d_in, const int* in_sizes, int n_in,
                              void* d_out, int out_size, void* d_ws, size_t ws_size,
                              hipStream_t stream) {
    (void)in_sizes; (void)n_in; (void)out_size;
    const float* fused = (const float*)d_in[0];
    const float* hf1   = (const float*)d_in[1];
    const float* hf2   = (const float*)d_in[2];
    const float* cw    = (const float*)d_in[3];
    const float* cb    = (const float*)d_in[4];
    float* out  = (float*)d_out;
    float* part = (float*)d_ws;

    dim3 cblk(64, 4, 1);
    const int redBlocks = LLSZ / 4 / 256;                        // 768
    const int iwtBlocks = (NB * 3 * H2 * W1) / 256;              // 6144

    const size_t need8 = (size_t)9 * LLSZ * sizeof(float);       // 28.3 MB
    if (ws_size >= need8) {
        float* ll = part + (size_t)8 * LLSZ;
        dim3 cgrd(8, 8, NB);                                     // 1024 blocks
        conv4_kernel<8><<<cgrd, cblk, 0, stream>>>(fused, cw, part);
        reduce_tanh_kernel<8><<<redBlocks, 256, 0, stream>>>(part, cb, ll);
        iwt_row2_kernel<<<iwtBlocks, 256, 0, stream>>>(ll, hf2, hf1, out);
    } else {
        // minimal-ws fallback: single chunk (6.3 MB)
        float* ll = part + (size_t)LLSZ;
        dim3 cgrd(1, 8, NB);                                     // 128 blocks
        conv4_kernel<64><<<cgrd, cblk, 0, stream>>>(fused, cw, part);
        reduce_tanh_kernel<1><<<redBlocks, 256, 0, stream>>>(part, cb, ll);
        iwt_row2_kernel<<<iwtBlocks, 256, 0, stream>>>(ll, hf2, hf1, out);
    }
}